// Round 5
// baseline (1026.842 us; speedup 1.0000x reference)
//
#include <hip/hip_runtime.h>
#include <hip/hip_bf16.h>
#include <stdint.h>

#define HID 256
#define GOD 200
#define LN_EPS 1e-5f
#define PB 128            // proteins per bucket
#define PBSH 7            // log2(PB)

typedef __attribute__((ext_vector_type(8))) short short8;
typedef __attribute__((ext_vector_type(4))) float f32x4;

__device__ __forceinline__ float bf2f(unsigned short u) {
    union { unsigned int i; float f; } c; c.i = ((unsigned int)u) << 16; return c.f;
}
__device__ __forceinline__ unsigned short f2bf(float f) {
    union { float f; unsigned int i; } c; c.f = f;
    unsigned int x = c.i;
    return (unsigned short)((x + 0x7fffu + ((x >> 16) & 1u)) >> 16);
}
__device__ __forceinline__ unsigned int pack2(float a, float b) {
    return (unsigned int)f2bf(a) | ((unsigned int)f2bf(b) << 16);
}
__device__ __forceinline__ short8 pack8(float4 a, float4 b) {
    short8 r;
    r[0] = (short)f2bf(a.x); r[1] = (short)f2bf(a.y);
    r[2] = (short)f2bf(a.z); r[3] = (short)f2bf(a.w);
    r[4] = (short)f2bf(b.x); r[5] = (short)f2bf(b.y);
    r[6] = (short)f2bf(b.z); r[7] = (short)f2bf(b.w);
    return r;
}

// ---------------- fused weight transpose + bf16 cast ----------------
// Wgt[256][256] (K=200 zero-padded), W1t[256][512], W2t[256][256]
__global__ void transpose_all_kernel(const float* __restrict__ Wg, const float* __restrict__ W1,
                                     const float* __restrict__ W2, short* __restrict__ Wgt,
                                     short* __restrict__ W1t, short* __restrict__ W2t) {
    const int TOT = 65536 + 131072 + 65536;
    for (int idx = blockIdx.x * 256 + threadIdx.x; idx < TOT; idx += gridDim.x * 256) {
        if (idx < 65536) {
            int c = idx >> 8, k = idx & 255;
            Wgt[idx] = (short)f2bf(k < GOD ? Wg[(size_t)k * 256 + c] : 0.f);
        } else if (idx < 65536 + 131072) {
            int j = idx - 65536;
            int c = j >> 9, k = j & 511;
            W1t[j] = (short)f2bf(W1[(size_t)k * 256 + c]);
        } else {
            int j = idx - (65536 + 131072);
            int c = j >> 8, k = j & 255;
            W2t[j] = (short)f2bf(W2[(size_t)k * 256 + c]);
        }
    }
}

// ---------------- MFMA GEMM (unchanged from r1, verified) ----------------
template<int K, int ASTRIDE, int AK, bool AF32, int EPI>
__global__ __launch_bounds__(256) void gemm_mfma(
        const void* __restrict__ Ap, const short* __restrict__ Bt,
        const float* __restrict__ bias, void* __restrict__ outp,
        const float* __restrict__ prot, const int* __restrict__ counts, int M) {
    __shared__ short As[128][88];
    __shared__ short Bs[128][88];

    const int t = threadIdx.x;
    const int row0 = blockIdx.x * 128;
    const int col0 = blockIdx.y * 128;
    const int lane = t & 63, w = t >> 6, wr = w >> 1, wc = w & 1;

    f32x4 acc[4][4] = {};

    for (int kt = 0; kt < K / 64; ++kt) {
        const int k0 = kt * 64;
        short8 ar[4], br[4];
#pragma unroll
        for (int i = 0; i < 4; ++i) {
            int seg = t + i * 256;
            int r = seg >> 3, co = (seg & 7) * 8;
            if (AF32) {
                short8 v = {};
                if (row0 + r < M && k0 + co + 8 <= AK) {
                    const float* ap = (const float*)Ap + (size_t)(row0 + r) * ASTRIDE + k0 + co;
                    float4 f0 = *(const float4*)ap;
                    float4 f1 = *(const float4*)(ap + 4);
                    v = pack8(f0, f1);
                }
                ar[i] = v;
            } else {
                short8 v = {};
                if (row0 + r < M)
                    v = *(const short8*)((const short*)Ap + (size_t)(row0 + r) * ASTRIDE + k0 + co);
                ar[i] = v;
            }
            br[i] = *(const short8*)(Bt + (size_t)(col0 + r) * K + k0 + co);
        }
        __syncthreads();
#pragma unroll
        for (int i = 0; i < 4; ++i) {
            int seg = t + i * 256;
            int r = seg >> 3, co = (seg & 7) * 8;
            *(short8*)&As[r][co] = ar[i];
            *(short8*)&Bs[r][co] = br[i];
        }
        __syncthreads();
#pragma unroll
        for (int ks = 0; ks < 2; ++ks) {
            short8 af[4], bf[4];
#pragma unroll
            for (int mt = 0; mt < 4; ++mt)
                af[mt] = *(const short8*)&As[wr * 64 + mt * 16 + (lane & 15)][ks * 32 + (lane >> 4) * 8];
#pragma unroll
            for (int nt = 0; nt < 4; ++nt)
                bf[nt] = *(const short8*)&Bs[wc * 64 + nt * 16 + (lane & 15)][ks * 32 + (lane >> 4) * 8];
#pragma unroll
            for (int mt = 0; mt < 4; ++mt)
#pragma unroll
                for (int nt = 0; nt < 4; ++nt)
                    acc[mt][nt] = __builtin_amdgcn_mfma_f32_16x16x32_bf16(af[mt], bf[nt], acc[mt][nt], 0, 0, 0);
        }
    }

#pragma unroll
    for (int nt = 0; nt < 4; ++nt) {
        int cg = col0 + wc * 64 + nt * 16 + (lane & 15);
        float bb = bias[cg];
#pragma unroll
        for (int mt = 0; mt < 4; ++mt) {
            int rbase = row0 + wr * 64 + mt * 16 + ((lane >> 4) * 4);
#pragma unroll
            for (int j = 0; j < 4; ++j) {
                int rg = rbase + j;
                if (rg < M) {
                    float v = acc[mt][nt][j] + bb;
                    if (EPI == 0) {
                        ((unsigned short*)outp)[(size_t)rg * 256 + cg] = f2bf(fmaxf(v, 0.f));
                    } else {
                        float pres = (counts[rg] > 0) ? 1.f : 0.f;
                        ((float*)outp)[(size_t)rg * 256 + cg] =
                            prot[(size_t)rg * 256 + cg] + pres * v;
                    }
                }
            }
        }
    }
}

// ---------------- bucketed CSR build ----------------
// passA: bucket histogram (LDS-staged)
__global__ __launch_bounds__(256) void bucket_hist_kernel(
        const int* __restrict__ dst, int* __restrict__ bcnt, int E, int NB) {
    __shared__ int h[512];
    int tid = threadIdx.x;
    for (int i = tid; i < NB; i += 256) h[i] = 0;
    __syncthreads();
    for (int e = blockIdx.x * 256 + tid; e < E; e += gridDim.x * 256)
        atomicAdd(&h[dst[e] >> PBSH], 1);
    __syncthreads();
    for (int i = tid; i < NB; i += 256)
        if (h[i]) atomicAdd(&bcnt[i], h[i]);
}

// bucket scan: NB <= 512
__global__ __launch_bounds__(512) void bucket_scan_kernel(
        const int* __restrict__ bcnt, int* __restrict__ base,
        int* __restrict__ cursor, int NB, int E) {
    __shared__ int sc[512];
    int tid = threadIdx.x;
    int v = (tid < NB) ? bcnt[tid] : 0;
    sc[tid] = v;
    __syncthreads();
    for (int o = 1; o < 512; o <<= 1) {
        int add = (tid >= o) ? sc[tid - o] : 0;
        __syncthreads();
        sc[tid] += add;
        __syncthreads();
    }
    int excl = sc[tid] - v;
    if (tid < NB) { base[tid] = excl; cursor[tid] = excl; }
    if (tid == NB) base[NB] = E;
}

// passB: append packed (dst&127)<<25 | src into bucket region (write-friendly)
__global__ __launch_bounds__(256) void bucket_scatter_kernel(
        const int* __restrict__ dst, const int* __restrict__ src,
        int* __restrict__ cursor, unsigned int* __restrict__ pairs, int E) {
    for (int e = blockIdx.x * 256 + threadIdx.x; e < E; e += gridDim.x * 256) {
        int d = dst[e];
        unsigned int v = ((unsigned int)(d & (PB - 1)) << 25) | (unsigned int)src[e];
        int slot = atomicAdd(&cursor[d >> PBSH], 1);
        pairs[slot] = v;
    }
}

// passC: per-bucket local CSR (hist + scan + place), writes counts/offsets/nbr
__global__ __launch_bounds__(256) void local_csr_kernel(
        const unsigned int* __restrict__ pairs, const int* __restrict__ base,
        int* __restrict__ counts, int* __restrict__ offsets, int* __restrict__ nbr, int N) {
    __shared__ int cnt[PB], sc[PB], cur[PB];
    int b = blockIdx.x, tid = threadIdx.x;
    int ebase = base[b], ecount = base[b + 1] - ebase;
    int p0 = b << PBSH;
    if (tid < PB) cnt[tid] = 0;
    __syncthreads();
    for (int i = tid; i < ecount; i += 256)
        atomicAdd(&cnt[pairs[ebase + i] >> 25], 1);
    __syncthreads();
    if (tid < PB) sc[tid] = cnt[tid];
    __syncthreads();
    for (int o = 1; o < PB; o <<= 1) {
        int add = (tid < PB && tid >= o) ? sc[tid - o] : 0;
        __syncthreads();
        if (tid < PB) sc[tid] += add;
        __syncthreads();
    }
    if (tid < PB) {
        int excl = sc[tid] - cnt[tid];
        int p = p0 + tid;
        if (p < N) { counts[p] = cnt[tid]; offsets[p] = ebase + excl; }
        cur[tid] = ebase + excl;
    }
    __syncthreads();
    for (int i = tid; i < ecount; i += 256) {
        unsigned int v = pairs[ebase + i];
        int slot = atomicAdd(&cur[v >> 25], 1);
        nbr[slot] = (int)(v & 0x1FFFFFFu);
    }
}

// ---------------- scatter-mean + prot cast: one wave per protein ----------------
__global__ void agg_kernel(const unsigned short* __restrict__ go_h,
                           const int* __restrict__ counts, const int* __restrict__ offsets,
                           const int* __restrict__ nbr, const float* __restrict__ prot,
                           unsigned short* __restrict__ hcat, int N) {
    int p = blockIdx.x;
    if (p >= N) return;
    int lane = threadIdx.x;  // 64
    // cast prot row -> hcat[:, :256]
    float4 pf = ((const float4*)(prot + (size_t)p * 256))[lane];
    unsigned int* hp = (unsigned int*)(hcat + (size_t)p * 512);
    hp[lane * 2]     = pack2(pf.x, pf.y);
    hp[lane * 2 + 1] = pack2(pf.z, pf.w);
    // aggregate
    int deg = counts[p], off = offsets[p];
    float a0 = 0.f, a1 = 0.f, a2 = 0.f, a3 = 0.f;
    for (int i = 0; i < deg; ++i) {
        int g = nbr[off + i];
        ushort4 u = *(const ushort4*)(go_h + (size_t)g * HID + lane * 4);
        a0 += bf2f(u.x); a1 += bf2f(u.y); a2 += bf2f(u.z); a3 += bf2f(u.w);
    }
    float inv = 1.f / (float)max(deg, 1);
    unsigned short* d = hcat + (size_t)p * 512 + HID + lane * 4;
    *(unsigned int*)(d)     = pack2(a0 * inv, a1 * inv);
    *(unsigned int*)(d + 2) = pack2(a2 * inv, a3 * inv);
}

// ---------------- LayerNorm over y[N][256] f32 -> out ----------------
__global__ __launch_bounds__(256) void ln_kernel(
        const float* __restrict__ y, const float* __restrict__ gamma,
        const float* __restrict__ beta, float* __restrict__ out, int N) {
    int lane = threadIdx.x & 63;
    int row = blockIdx.x * 4 + (threadIdx.x >> 6);
    if (row >= N) return;
    float4 v = ((const float4*)(y + (size_t)row * 256))[lane];
    float s = v.x + v.y + v.z + v.w;
#pragma unroll
    for (int o = 32; o >= 1; o >>= 1) s += __shfl_xor(s, o);
    float mu = s * (1.f / 256.f);
    float4 d; d.x = v.x - mu; d.y = v.y - mu; d.z = v.z - mu; d.w = v.w - mu;
    float q = d.x * d.x + d.y * d.y + d.z * d.z + d.w * d.w;
#pragma unroll
    for (int o = 32; o >= 1; o >>= 1) q += __shfl_xor(q, o);
    float rstd = rsqrtf(q * (1.f / 256.f) + LN_EPS);
    float4 g = ((const float4*)gamma)[lane];
    float4 b = ((const float4*)beta)[lane];
    float4 o4;
    o4.x = d.x * rstd * g.x + b.x; o4.y = d.y * rstd * g.y + b.y;
    o4.z = d.z * rstd * g.z + b.z; o4.w = d.w * rstd * g.w + b.w;
    ((float4*)(out + (size_t)row * 256))[lane] = o4;
}

extern "C" void kernel_launch(void* const* d_in, const int* in_sizes, int n_in,
                              void* d_out, int out_size, void* d_ws, size_t ws_size,
                              hipStream_t stream) {
    const float* prot  = (const float*)d_in[0];
    const float* go_x  = (const float*)d_in[1];
    const int*   edges = (const int*)d_in[2];
    const float* Wg    = (const float*)d_in[4];
    const float* bg    = (const float*)d_in[5];
    const float* W1    = (const float*)d_in[6];
    const float* b1    = (const float*)d_in[7];
    const float* W2    = (const float*)d_in[8];
    const float* b2    = (const float*)d_in[9];
    const float* gamma = (const float*)d_in[10];
    const float* beta  = (const float*)d_in[11];

    int N = in_sizes[0] / HID;
    int G = in_sizes[1] / GOD;
    int E = in_sizes[2] / 2;
    const int* dst = edges;
    const int* src = edges + E;
    int NB = (N + PB - 1) / PB;   // 391 for N=50000 (must be <= 512)

    uint8_t* w = (uint8_t*)d_ws;
    size_t off = 0;
    auto alloc = [&](size_t bytes) -> void* {
        void* p = w + off;
        off = (off + bytes + 255) & ~(size_t)255;
        return p;
    };
    unsigned short* go_h = (unsigned short*)alloc((size_t)G * HID * 2);
    unsigned short* hcat = (unsigned short*)alloc((size_t)N * 512 * 2);
    unsigned short* tmp  = (unsigned short*)alloc((size_t)N * HID * 2);
    int* counts  = (int*)alloc((size_t)N * 4);
    int* offsets = (int*)alloc((size_t)N * 4);
    int* nbr     = (int*)alloc((size_t)E * 4);
    int* bcnt    = (int*)alloc((size_t)(NB + 1) * 4);
    int* bbase   = (int*)alloc((size_t)(NB + 1) * 4);
    int* bcur    = (int*)alloc((size_t)(NB + 1) * 4);
    short* Wgt = (short*)alloc((size_t)256 * 256 * 2);
    short* W1t = (short*)alloc((size_t)256 * 512 * 2);
    short* W2t = (short*)alloc((size_t)256 * 256 * 2);
    unsigned int* pairs = (unsigned int*)tmp;  // alias: tmp unused until mlp1 (pairs dead by then)
    float* y = (float*)hcat;                   // alias: hcat dead after mlp1

    hipMemsetAsync(bcnt, 0, (size_t)NB * 4, stream);

    transpose_all_kernel<<<dim3(256), dim3(256), 0, stream>>>(Wg, W1, W2, Wgt, W1t, W2t);

    int rb = (N + 127) / 128;
    int rbg = (G + 127) / 128;

    // go_h = relu(go_x @ Wg + bg)   [A f32, K padded 200->256]
    gemm_mfma<256, GOD, GOD, true, 0><<<dim3(rbg, 2), dim3(256), 0, stream>>>(
        go_x, Wgt, bg, go_h, nullptr, nullptr, G);

    // bucketed CSR build
    bucket_hist_kernel<<<dim3(2048), dim3(256), 0, stream>>>(dst, bcnt, E, NB);
    bucket_scan_kernel<<<dim3(1), dim3(512), 0, stream>>>(bcnt, bbase, bcur, NB, E);
    bucket_scatter_kernel<<<dim3(2048), dim3(256), 0, stream>>>(dst, src, bcur, pairs, E);
    local_csr_kernel<<<dim3(NB), dim3(256), 0, stream>>>(pairs, bbase, counts, offsets, nbr, N);

    // scatter-mean + prot cast
    agg_kernel<<<dim3(N), dim3(64), 0, stream>>>(go_h, counts, offsets, nbr, prot, hcat, N);

    // tmp = relu(hcat @ W1 + b1)
    gemm_mfma<512, 512, 512, false, 0><<<dim3(rb, 2), dim3(256), 0, stream>>>(
        hcat, W1t, b1, tmp, nullptr, nullptr, N);

    // y = prot + present * (tmp @ W2 + b2)
    gemm_mfma<256, 256, 256, false, 1><<<dim3(rb, 2), dim3(256), 0, stream>>>(
        tmp, W2t, b2, y, prot, counts, N);

    ln_kernel<<<dim3((N + 3) / 4), dim3(256), 0, stream>>>(y, gamma, beta, (float*)d_out, N);
}

// Round 7
// 972.947 us; speedup vs baseline: 1.0554x; 1.0554x over previous
//
#include <hip/hip_runtime.h>
#include <hip/hip_bf16.h>
#include <stdint.h>

#define HID 256
#define GOD 200
#define LN_EPS 1e-5f
#define PB 64             // proteins per bucket
#define PBSH 6
#define NBLK 128          // partition blocks
#define MAXNB 800         // LDS array bound (NB = ceil(N/64) = 782)

typedef __attribute__((ext_vector_type(8))) short short8;
typedef __attribute__((ext_vector_type(4))) float f32x4;

__device__ __forceinline__ float bf2f(unsigned short u) {
    union { unsigned int i; float f; } c; c.i = ((unsigned int)u) << 16; return c.f;
}
__device__ __forceinline__ unsigned short f2bf(float f) {
    union { float f; unsigned int i; } c; c.f = f;
    unsigned int x = c.i;
    return (unsigned short)((x + 0x7fffu + ((x >> 16) & 1u)) >> 16);
}
__device__ __forceinline__ unsigned int pack2(float a, float b) {
    return (unsigned int)f2bf(a) | ((unsigned int)f2bf(b) << 16);
}
__device__ __forceinline__ short8 pack8(float4 a, float4 b) {
    short8 r;
    r[0] = (short)f2bf(a.x); r[1] = (short)f2bf(a.y);
    r[2] = (short)f2bf(a.z); r[3] = (short)f2bf(a.w);
    r[4] = (short)f2bf(b.x); r[5] = (short)f2bf(b.y);
    r[6] = (short)f2bf(b.z); r[7] = (short)f2bf(b.w);
    return r;
}

// ---------------- fused weight transpose + bf16 cast ----------------
__global__ void transpose_all_kernel(const float* __restrict__ Wg, const float* __restrict__ W1,
                                     const float* __restrict__ W2, short* __restrict__ Wgt,
                                     short* __restrict__ W1t, short* __restrict__ W2t) {
    const int TOT = 65536 + 131072 + 65536;
    for (int idx = blockIdx.x * 256 + threadIdx.x; idx < TOT; idx += gridDim.x * 256) {
        if (idx < 65536) {
            int c = idx >> 8, k = idx & 255;
            Wgt[idx] = (short)f2bf(k < GOD ? Wg[(size_t)k * 256 + c] : 0.f);
        } else if (idx < 65536 + 131072) {
            int j = idx - 65536;
            int c = j >> 9, k = j & 511;
            W1t[j] = (short)f2bf(W1[(size_t)k * 256 + c]);
        } else {
            int j = idx - (65536 + 131072);
            int c = j >> 8, k = j & 255;
            W2t[j] = (short)f2bf(W2[(size_t)k * 256 + c]);
        }
    }
}

// ---------------- MFMA GEMM (verified r4) ----------------
template<int K, int ASTRIDE, int AK, bool AF32, int EPI>
__global__ __launch_bounds__(256) void gemm_mfma(
        const void* __restrict__ Ap, const short* __restrict__ Bt,
        const float* __restrict__ bias, void* __restrict__ outp,
        const float* __restrict__ prot, const int* __restrict__ counts, int M) {
    __shared__ short As[128][88];
    __shared__ short Bs[128][88];

    const int t = threadIdx.x;
    const int row0 = blockIdx.x * 128;
    const int col0 = blockIdx.y * 128;
    const int lane = t & 63, w = t >> 6, wr = w >> 1, wc = w & 1;

    f32x4 acc[4][4] = {};

    for (int kt = 0; kt < K / 64; ++kt) {
        const int k0 = kt * 64;
        short8 ar[4], br[4];
#pragma unroll
        for (int i = 0; i < 4; ++i) {
            int seg = t + i * 256;
            int r = seg >> 3, co = (seg & 7) * 8;
            if (AF32) {
                short8 v = {};
                if (row0 + r < M && k0 + co + 8 <= AK) {
                    const float* ap = (const float*)Ap + (size_t)(row0 + r) * ASTRIDE + k0 + co;
                    float4 f0 = *(const float4*)ap;
                    float4 f1 = *(const float4*)(ap + 4);
                    v = pack8(f0, f1);
                }
                ar[i] = v;
            } else {
                short8 v = {};
                if (row0 + r < M)
                    v = *(const short8*)((const short*)Ap + (size_t)(row0 + r) * ASTRIDE + k0 + co);
                ar[i] = v;
            }
            br[i] = *(const short8*)(Bt + (size_t)(col0 + r) * K + k0 + co);
        }
        __syncthreads();
#pragma unroll
        for (int i = 0; i < 4; ++i) {
            int seg = t + i * 256;
            int r = seg >> 3, co = (seg & 7) * 8;
            *(short8*)&As[r][co] = ar[i];
            *(short8*)&Bs[r][co] = br[i];
        }
        __syncthreads();
#pragma unroll
        for (int ks = 0; ks < 2; ++ks) {
            short8 af[4], bf[4];
#pragma unroll
            for (int mt = 0; mt < 4; ++mt)
                af[mt] = *(const short8*)&As[wr * 64 + mt * 16 + (lane & 15)][ks * 32 + (lane >> 4) * 8];
#pragma unroll
            for (int nt = 0; nt < 4; ++nt)
                bf[nt] = *(const short8*)&Bs[wc * 64 + nt * 16 + (lane & 15)][ks * 32 + (lane >> 4) * 8];
#pragma unroll
            for (int mt = 0; mt < 4; ++mt)
#pragma unroll
                for (int nt = 0; nt < 4; ++nt)
                    acc[mt][nt] = __builtin_amdgcn_mfma_f32_16x16x32_bf16(af[mt], bf[nt], acc[mt][nt], 0, 0, 0);
        }
    }

#pragma unroll
    for (int nt = 0; nt < 4; ++nt) {
        int cg = col0 + wc * 64 + nt * 16 + (lane & 15);
        float bb = bias[cg];
#pragma unroll
        for (int mt = 0; mt < 4; ++mt) {
            int rbase = row0 + wr * 64 + mt * 16 + ((lane >> 4) * 4);
#pragma unroll
            for (int j = 0; j < 4; ++j) {
                int rg = rbase + j;
                if (rg < M) {
                    float v = acc[mt][nt][j] + bb;
                    if (EPI == 0) {
                        ((unsigned short*)outp)[(size_t)rg * 256 + cg] = f2bf(fmaxf(v, 0.f));
                    } else {
                        float pres = (counts[rg] > 0) ? 1.f : 0.f;
                        ((float*)outp)[(size_t)rg * 256 + cg] =
                            prot[(size_t)rg * 256 + cg] + pres * v;
                    }
                }
            }
        }
    }
}

// ---------------- counting-sort partition ----------------
// passA: per-block bucket histogram -> blk_cnt[bucket][block]  (no global atomics)
__global__ __launch_bounds__(256) void blk_hist_kernel(
        const int* __restrict__ dst, int* __restrict__ blk_cnt, int E, int NB, int chunk) {
    __shared__ int h[MAXNB];
    int k = blockIdx.x, tid = threadIdx.x;
    for (int i = tid; i < NB; i += 256) h[i] = 0;
    __syncthreads();
    int s0 = k * chunk, s1 = min(E, s0 + chunk);
    for (int e = s0 + tid; e < s1; e += 256) atomicAdd(&h[dst[e] >> PBSH], 1);
    __syncthreads();
    for (int i = tid; i < NB; i += 256) blk_cnt[(size_t)i * NBLK + k] = h[i];
}

// scanA: one wave per bucket, exclusive scan over the 128 block counts
__global__ __launch_bounds__(64) void blk_scan_kernel(
        const int* __restrict__ blk_cnt, int* __restrict__ blk_off, int* __restrict__ btot) {
    int b = blockIdx.x, l = threadIdx.x;
    int v0 = blk_cnt[(size_t)b * NBLK + 2 * l];
    int v1 = blk_cnt[(size_t)b * NBLK + 2 * l + 1];
    int s = v0 + v1;
#pragma unroll
    for (int o = 1; o < 64; o <<= 1) { int y = __shfl_up(s, o); if (l >= o) s += y; }
    int excl = s - (v0 + v1);
    blk_off[(size_t)b * NBLK + 2 * l]     = excl;
    blk_off[(size_t)b * NBLK + 2 * l + 1] = excl + v0;
    if (l == 63) btot[b] = s;
}

// scanB: exclusive scan over bucket totals (NB <= 1024)
__global__ __launch_bounds__(1024) void bucket_scan_kernel(
        const int* __restrict__ btot, int* __restrict__ bbase, int NB, int E) {
    __shared__ int sc[1024];
    int tid = threadIdx.x;
    int v = (tid < NB) ? btot[tid] : 0;
    sc[tid] = v;
    __syncthreads();
    for (int o = 1; o < 1024; o <<= 1) {
        int add = (tid >= o) ? sc[tid - o] : 0;
        __syncthreads();
        sc[tid] += add;
        __syncthreads();
    }
    if (tid < NB) bbase[tid] = sc[tid] - v;
    if (tid == 0) bbase[NB] = E;
}

// passB: place packed (dlow<<16 | src) records; cursors in LDS (deterministic bases)
__global__ __launch_bounds__(256) void part_kernel(
        const int* __restrict__ dst, const int* __restrict__ src,
        const int* __restrict__ bbase, const int* __restrict__ blk_off,
        unsigned int* __restrict__ pairs, int E, int NB, int chunk) {
    __shared__ int cur[MAXNB];
    int k = blockIdx.x, tid = threadIdx.x;
    for (int i = tid; i < NB; i += 256)
        cur[i] = bbase[i] + blk_off[(size_t)i * NBLK + k];
    __syncthreads();
    int s0 = k * chunk, s1 = min(E, s0 + chunk);
    for (int e = s0 + tid; e < s1; e += 256) {
        int d = dst[e];
        unsigned int pr = ((unsigned int)(d & (PB - 1)) << 16) | (unsigned int)src[e];
        int slot = atomicAdd(&cur[d >> PBSH], 1);
        pairs[slot] = pr;
    }
}

// ---------------- fused bucket aggregation + prot cast ----------------
// one block per bucket; sums[64][256] f32 in LDS; wave w owns dims [64w, 64w+64)
__global__ __launch_bounds__(256) void agg_kernel(
        const unsigned short* __restrict__ go_h, const unsigned int* __restrict__ pairs,
        const int* __restrict__ bbase, const float* __restrict__ prot,
        unsigned short* __restrict__ hcat, int* __restrict__ counts, int N) {
    __shared__ float sums[PB][256];
    __shared__ int cnt[PB];
    int b = blockIdx.x, tid = threadIdx.x, w = tid >> 6, l = tid & 63;
    int dim = w * 64 + l;
    for (int i = tid; i < PB * 256; i += 256) ((float*)sums)[i] = 0.f;
    if (tid < PB) cnt[tid] = 0;
    __syncthreads();

    int e0 = bbase[b], e1 = bbase[b + 1];
    int i = e0;
    for (; i + 4 <= e1; i += 4) {
        unsigned int p0 = pairs[i], p1 = pairs[i + 1], p2 = pairs[i + 2], p3 = pairs[i + 3];
        float v0 = bf2f(go_h[(size_t)(p0 & 0xffffu) * 256 + dim]);
        float v1 = bf2f(go_h[(size_t)(p1 & 0xffffu) * 256 + dim]);
        float v2 = bf2f(go_h[(size_t)(p2 & 0xffffu) * 256 + dim]);
        float v3 = bf2f(go_h[(size_t)(p3 & 0xffffu) * 256 + dim]);
        sums[p0 >> 16][dim] += v0;
        sums[p1 >> 16][dim] += v1;
        sums[p2 >> 16][dim] += v2;
        sums[p3 >> 16][dim] += v3;
        if (tid == 0) { cnt[p0 >> 16]++; cnt[p1 >> 16]++; cnt[p2 >> 16]++; cnt[p3 >> 16]++; }
    }
    for (; i < e1; ++i) {
        unsigned int pr = pairs[i];
        float v = bf2f(go_h[(size_t)(pr & 0xffffu) * 256 + dim]);
        sums[pr >> 16][dim] += v;
        if (tid == 0) cnt[pr >> 16]++;
    }
    __syncthreads();

    int p0g = b << PBSH;
    for (int r = w; r < PB; r += 4) {
        int p = p0g + r;
        if (p >= N) break;
        int c = cnt[r];
        float inv = 1.f / (float)max(c, 1);
        float4 pf = ((const float4*)(prot + (size_t)p * 256))[l];
        unsigned int* hp = (unsigned int*)(hcat + (size_t)p * 512);
        hp[2 * l]     = pack2(pf.x, pf.y);
        hp[2 * l + 1] = pack2(pf.z, pf.w);
        float4 sv = *(float4*)&sums[r][l * 4];
        unsigned int* hq = hp + 128 + 2 * l;
        hq[0] = pack2(sv.x * inv, sv.y * inv);
        hq[1] = pack2(sv.z * inv, sv.w * inv);
        if (l == 0) counts[p] = c;
    }
}

// ---------------- LayerNorm over y[N][256] f32 -> out ----------------
__global__ __launch_bounds__(256) void ln_kernel(
        const float* __restrict__ y, const float* __restrict__ gamma,
        const float* __restrict__ beta, float* __restrict__ out, int N) {
    int lane = threadIdx.x & 63;
    int row = blockIdx.x * 4 + (threadIdx.x >> 6);
    if (row >= N) return;
    float4 v = ((const float4*)(y + (size_t)row * 256))[lane];
    float s = v.x + v.y + v.z + v.w;
#pragma unroll
    for (int o = 32; o >= 1; o >>= 1) s += __shfl_xor(s, o);
    float mu = s * (1.f / 256.f);
    float4 d; d.x = v.x - mu; d.y = v.y - mu; d.z = v.z - mu; d.w = v.w - mu;
    float q = d.x * d.x + d.y * d.y + d.z * d.z + d.w * d.w;
#pragma unroll
    for (int o = 32; o >= 1; o >>= 1) q += __shfl_xor(q, o);
    float rstd = rsqrtf(q * (1.f / 256.f) + LN_EPS);
    float4 g = ((const float4*)gamma)[lane];
    float4 b = ((const float4*)beta)[lane];
    float4 o4;
    o4.x = d.x * rstd * g.x + b.x; o4.y = d.y * rstd * g.y + b.y;
    o4.z = d.z * rstd * g.z + b.z; o4.w = d.w * rstd * g.w + b.w;
    ((float4*)(out + (size_t)row * 256))[lane] = o4;
}

extern "C" void kernel_launch(void* const* d_in, const int* in_sizes, int n_in,
                              void* d_out, int out_size, void* d_ws, size_t ws_size,
                              hipStream_t stream) {
    const float* prot  = (const float*)d_in[0];
    const float* go_x  = (const float*)d_in[1];
    const int*   edges = (const int*)d_in[2];
    const float* Wg    = (const float*)d_in[4];
    const float* bg    = (const float*)d_in[5];
    const float* W1    = (const float*)d_in[6];
    const float* b1    = (const float*)d_in[7];
    const float* W2    = (const float*)d_in[8];
    const float* b2    = (const float*)d_in[9];
    const float* gamma = (const float*)d_in[10];
    const float* beta  = (const float*)d_in[11];

    int N = in_sizes[0] / HID;
    int G = in_sizes[1] / GOD;
    int E = in_sizes[2] / 2;
    const int* dst = edges;
    const int* src = edges + E;
    int NB = (N + PB - 1) / PB;          // 782 for N=50000 (<= MAXNB)
    int chunk = (E + NBLK - 1) / NBLK;   // 12500

    uint8_t* w = (uint8_t*)d_ws;
    size_t off = 0;
    auto alloc = [&](size_t bytes) -> void* {
        void* p = w + off;
        off = (off + bytes + 255) & ~(size_t)255;
        return p;
    };
    unsigned short* go_h = (unsigned short*)alloc((size_t)G * HID * 2);
    unsigned short* hcat = (unsigned short*)alloc((size_t)N * 512 * 2);
    unsigned short* tmp  = (unsigned short*)alloc((size_t)N * HID * 2);
    int* counts  = (int*)alloc((size_t)N * 4);
    int* blk_cnt = (int*)alloc((size_t)NB * NBLK * 4);
    int* blk_off = (int*)alloc((size_t)NB * NBLK * 4);
    int* btot    = (int*)alloc((size_t)NB * 4);
    int* bbase   = (int*)alloc((size_t)(NB + 1) * 4);
    short* Wgt = (short*)alloc((size_t)256 * 256 * 2);
    short* W1t = (short*)alloc((size_t)256 * 512 * 2);
    short* W2t = (short*)alloc((size_t)256 * 256 * 2);
    unsigned int* pairs = (unsigned int*)tmp;  // alias: tmp unused until mlp1 (pairs dead by then)
    float* y = (float*)hcat;                   // alias: hcat dead after mlp1

    transpose_all_kernel<<<dim3(256), dim3(256), 0, stream>>>(Wg, W1, W2, Wgt, W1t, W2t);

    int rb = (N + 127) / 128;
    int rbg = (G + 127) / 128;

    // go_h = relu(go_x @ Wg + bg)   [A f32, K padded 200->256]
    gemm_mfma<256, GOD, GOD, true, 0><<<dim3(rbg, 2), dim3(256), 0, stream>>>(
        go_x, Wgt, bg, go_h, nullptr, nullptr, G);

    // deterministic counting-sort partition of edges into buckets
    blk_hist_kernel<<<dim3(NBLK), dim3(256), 0, stream>>>(dst, blk_cnt, E, NB, chunk);
    blk_scan_kernel<<<dim3(NB), dim3(64), 0, stream>>>(blk_cnt, blk_off, btot);
    bucket_scan_kernel<<<dim3(1), dim3(1024), 0, stream>>>(btot, bbase, NB, E);
    part_kernel<<<dim3(NBLK), dim3(256), 0, stream>>>(dst, src, bbase, blk_off, pairs, E, NB, chunk);

    // fused scatter-mean + prot cast
    agg_kernel<<<dim3(NB), dim3(256), 0, stream>>>(go_h, pairs, bbase, prot, hcat, counts, N);

    // tmp = relu(hcat @ W1 + b1)
    gemm_mfma<512, 512, 512, false, 0><<<dim3(rb, 2), dim3(256), 0, stream>>>(
        hcat, W1t, b1, tmp, nullptr, nullptr, N);

    // y = prot + present * (tmp @ W2 + b2)
    gemm_mfma<256, 256, 256, false, 1><<<dim3(rb, 2), dim3(256), 0, stream>>>(
        tmp, W2t, b2, y, prot, counts, N);

    ln_kernel<<<dim3((N + 3) / 4), dim3(256), 0, stream>>>(y, gamma, beta, (float*)d_out, N);
}

// Round 10
// 474.109 us; speedup vs baseline: 2.1658x; 2.0522x over previous
//
#include <hip/hip_runtime.h>
#include <hip/hip_bf16.h>
#include <stdint.h>

#define HID 256
#define GOD 200
#define LN_EPS 1e-5f
#define PB 64             // proteins per bucket
#define PBSH 6
#define NBLK 128          // partition blocks
#define MAXNB 800         // LDS array bound (NB = ceil(N/64) = 782)
#define CAP 6144          // staged edges per bucket (mean 2048, max ~2300 for this data)

typedef __attribute__((ext_vector_type(8))) short short8;
typedef __attribute__((ext_vector_type(4))) float f32x4;

__device__ __forceinline__ float bf2f(unsigned short u) {
    union { unsigned int i; float f; } c; c.i = ((unsigned int)u) << 16; return c.f;
}
__device__ __forceinline__ unsigned short f2bf(float f) {
    union { float f; unsigned int i; } c; c.f = f;
    unsigned int x = c.i;
    return (unsigned short)((x + 0x7fffu + ((x >> 16) & 1u)) >> 16);
}
__device__ __forceinline__ unsigned int pack2(float a, float b) {
    return (unsigned int)f2bf(a) | ((unsigned int)f2bf(b) << 16);
}
__device__ __forceinline__ short8 pack8(float4 a, float4 b) {
    short8 r;
    r[0] = (short)f2bf(a.x); r[1] = (short)f2bf(a.y);
    r[2] = (short)f2bf(a.z); r[3] = (short)f2bf(a.w);
    r[4] = (short)f2bf(b.x); r[5] = (short)f2bf(b.y);
    r[6] = (short)f2bf(b.z); r[7] = (short)f2bf(b.w);
    return r;
}

// ---------------- fused weight transpose + bf16 cast ----------------
__global__ void transpose_all_kernel(const float* __restrict__ Wg, const float* __restrict__ W1,
                                     const float* __restrict__ W2, short* __restrict__ Wgt,
                                     short* __restrict__ W1t, short* __restrict__ W2t) {
    const int TOT = 65536 + 131072 + 65536;
    for (int idx = blockIdx.x * 256 + threadIdx.x; idx < TOT; idx += gridDim.x * 256) {
        if (idx < 65536) {
            int c = idx >> 8, k = idx & 255;
            Wgt[idx] = (short)f2bf(k < GOD ? Wg[(size_t)k * 256 + c] : 0.f);
        } else if (idx < 65536 + 131072) {
            int j = idx - 65536;
            int c = j >> 9, k = j & 511;
            W1t[j] = (short)f2bf(W1[(size_t)k * 256 + c]);
        } else {
            int j = idx - (65536 + 131072);
            int c = j >> 8, k = j & 255;
            W2t[j] = (short)f2bf(W2[(size_t)k * 256 + c]);
        }
    }
}

// ---------------- MFMA GEMM (verified r4) ----------------
template<int K, int ASTRIDE, int AK, bool AF32, int EPI>
__global__ __launch_bounds__(256) void gemm_mfma(
        const void* __restrict__ Ap, const short* __restrict__ Bt,
        const float* __restrict__ bias, void* __restrict__ outp,
        const float* __restrict__ prot, const int* __restrict__ counts, int M) {
    __shared__ short As[128][88];
    __shared__ short Bs[128][88];

    const int t = threadIdx.x;
    const int row0 = blockIdx.x * 128;
    const int col0 = blockIdx.y * 128;
    const int lane = t & 63, w = t >> 6, wr = w >> 1, wc = w & 1;

    f32x4 acc[4][4] = {};

    for (int kt = 0; kt < K / 64; ++kt) {
        const int k0 = kt * 64;
        short8 ar[4], br[4];
#pragma unroll
        for (int i = 0; i < 4; ++i) {
            int seg = t + i * 256;
            int r = seg >> 3, co = (seg & 7) * 8;
            if (AF32) {
                short8 v = {};
                if (row0 + r < M && k0 + co + 8 <= AK) {
                    const float* ap = (const float*)Ap + (size_t)(row0 + r) * ASTRIDE + k0 + co;
                    float4 f0 = *(const float4*)ap;
                    float4 f1 = *(const float4*)(ap + 4);
                    v = pack8(f0, f1);
                }
                ar[i] = v;
            } else {
                short8 v = {};
                if (row0 + r < M)
                    v = *(const short8*)((const short*)Ap + (size_t)(row0 + r) * ASTRIDE + k0 + co);
                ar[i] = v;
            }
            br[i] = *(const short8*)(Bt + (size_t)(col0 + r) * K + k0 + co);
        }
        __syncthreads();
#pragma unroll
        for (int i = 0; i < 4; ++i) {
            int seg = t + i * 256;
            int r = seg >> 3, co = (seg & 7) * 8;
            *(short8*)&As[r][co] = ar[i];
            *(short8*)&Bs[r][co] = br[i];
        }
        __syncthreads();
#pragma unroll
        for (int ks = 0; ks < 2; ++ks) {
            short8 af[4], bf[4];
#pragma unroll
            for (int mt = 0; mt < 4; ++mt)
                af[mt] = *(const short8*)&As[wr * 64 + mt * 16 + (lane & 15)][ks * 32 + (lane >> 4) * 8];
#pragma unroll
            for (int nt = 0; nt < 4; ++nt)
                bf[nt] = *(const short8*)&Bs[wc * 64 + nt * 16 + (lane & 15)][ks * 32 + (lane >> 4) * 8];
#pragma unroll
            for (int mt = 0; mt < 4; ++mt)
#pragma unroll
                for (int nt = 0; nt < 4; ++nt)
                    acc[mt][nt] = __builtin_amdgcn_mfma_f32_16x16x32_bf16(af[mt], bf[nt], acc[mt][nt], 0, 0, 0);
        }
    }

#pragma unroll
    for (int nt = 0; nt < 4; ++nt) {
        int cg = col0 + wc * 64 + nt * 16 + (lane & 15);
        float bb = bias[cg];
#pragma unroll
        for (int mt = 0; mt < 4; ++mt) {
            int rbase = row0 + wr * 64 + mt * 16 + ((lane >> 4) * 4);
#pragma unroll
            for (int j = 0; j < 4; ++j) {
                int rg = rbase + j;
                if (rg < M) {
                    float v = acc[mt][nt][j] + bb;
                    if (EPI == 0) {
                        ((unsigned short*)outp)[(size_t)rg * 256 + cg] = f2bf(fmaxf(v, 0.f));
                    } else {
                        float pres = (counts[rg] > 0) ? 1.f : 0.f;
                        ((float*)outp)[(size_t)rg * 256 + cg] =
                            prot[(size_t)rg * 256 + cg] + pres * v;
                    }
                }
            }
        }
    }
}

// ---------------- counting-sort partition ----------------
__global__ __launch_bounds__(256) void blk_hist_kernel(
        const int* __restrict__ dst, int* __restrict__ blk_cnt, int E, int NB, int chunk) {
    __shared__ int h[MAXNB];
    int k = blockIdx.x, tid = threadIdx.x;
    for (int i = tid; i < NB; i += 256) h[i] = 0;
    __syncthreads();
    int s0 = k * chunk, s1 = min(E, s0 + chunk);
    for (int e = s0 + tid; e < s1; e += 256) atomicAdd(&h[dst[e] >> PBSH], 1);
    __syncthreads();
    for (int i = tid; i < NB; i += 256) blk_cnt[(size_t)i * NBLK + k] = h[i];
}

__global__ __launch_bounds__(64) void blk_scan_kernel(
        const int* __restrict__ blk_cnt, int* __restrict__ blk_off, int* __restrict__ btot) {
    int b = blockIdx.x, l = threadIdx.x;
    int v0 = blk_cnt[(size_t)b * NBLK + 2 * l];
    int v1 = blk_cnt[(size_t)b * NBLK + 2 * l + 1];
    int s = v0 + v1;
#pragma unroll
    for (int o = 1; o < 64; o <<= 1) { int y = __shfl_up(s, o); if (l >= o) s += y; }
    int excl = s - (v0 + v1);
    blk_off[(size_t)b * NBLK + 2 * l]     = excl;
    blk_off[(size_t)b * NBLK + 2 * l + 1] = excl + v0;
    if (l == 63) btot[b] = s;
}

__global__ __launch_bounds__(1024) void bucket_scan_kernel(
        const int* __restrict__ btot, int* __restrict__ bbase, int NB, int E) {
    __shared__ int sc[1024];
    int tid = threadIdx.x;
    int v = (tid < NB) ? btot[tid] : 0;
    sc[tid] = v;
    __syncthreads();
    for (int o = 1; o < 1024; o <<= 1) {
        int add = (tid >= o) ? sc[tid - o] : 0;
        __syncthreads();
        sc[tid] += add;
        __syncthreads();
    }
    if (tid < NB) bbase[tid] = sc[tid] - v;
    if (tid == 0) bbase[NB] = E;
}

__global__ __launch_bounds__(256) void part_kernel(
        const int* __restrict__ dst, const int* __restrict__ src,
        const int* __restrict__ bbase, const int* __restrict__ blk_off,
        unsigned int* __restrict__ pairs, int E, int NB, int chunk) {
    __shared__ int cur[MAXNB];
    int k = blockIdx.x, tid = threadIdx.x;
    for (int i = tid; i < NB; i += 256)
        cur[i] = bbase[i] + blk_off[(size_t)i * NBLK + k];
    __syncthreads();
    int s0 = k * chunk, s1 = min(E, s0 + chunk);
    for (int e = s0 + tid; e < s1; e += 256) {
        int d = dst[e];
        unsigned int pr = ((unsigned int)(d & (PB - 1)) << 16) | (unsigned int)src[e];
        int slot = atomicAdd(&cur[d >> PBSH], 1);
        pairs[slot] = pr;
    }
}

// ---------------- aggregation: per-bucket local sort + wave-per-protein reg accum ----------------
__global__ __launch_bounds__(256) void agg_kernel(
        const unsigned short* __restrict__ go_h, const unsigned int* __restrict__ pairs,
        const int* __restrict__ bbase, const float* __restrict__ prot,
        unsigned short* __restrict__ hcat, int* __restrict__ counts, int N) {
    __shared__ unsigned short srt[CAP];
    __shared__ int cnt[PB], off[PB], cur[PB];
    int b = blockIdx.x, tid = threadIdx.x, w = tid >> 6, l = tid & 63;
    int e0 = bbase[b], e1 = bbase[b + 1];
    int ec = e1 - e0;
    int ecs = min(ec, CAP);   // staged (sorted) portion; overflow handled at the end

    if (tid < PB) cnt[tid] = 0;
    __syncthreads();
    // histogram over staged edges
    for (int i = tid; i < ecs; i += 256)
        atomicAdd(&cnt[pairs[e0 + i] >> 16], 1);
    __syncthreads();
    // 64-bin exclusive scan (wave 0)
    if (w == 0) {
        int v = cnt[l];
        int s = v;
#pragma unroll
        for (int o = 1; o < 64; o <<= 1) { int y = __shfl_up(s, o); if (l >= o) s += y; }
        off[l] = s - v;
        cur[l] = s - v;
    }
    __syncthreads();
    // place src u16 into per-protein segments
    for (int i = tid; i < ecs; i += 256) {
        unsigned int pr = pairs[e0 + i];
        int slot = atomicAdd(&cur[pr >> 16], 1);
        srt[slot] = (unsigned short)(pr & 0xffffu);
    }
    __syncthreads();

    // wave-per-protein register accumulation
    int p0g = b << PBSH;
    for (int r = w; r < PB; r += 4) {
        int p = p0g + r;
        if (p >= N) break;
        int o0 = off[r], d = cnt[r];
        float a0 = 0.f, a1 = 0.f, a2 = 0.f, a3 = 0.f;
        int i = 0;
        for (; i + 4 <= d; i += 4) {
            int g0 = srt[o0 + i], g1 = srt[o0 + i + 1];
            int g2 = srt[o0 + i + 2], g3 = srt[o0 + i + 3];
            ushort4 u0 = *(const ushort4*)(go_h + (size_t)g0 * 256 + l * 4);
            ushort4 u1 = *(const ushort4*)(go_h + (size_t)g1 * 256 + l * 4);
            ushort4 u2 = *(const ushort4*)(go_h + (size_t)g2 * 256 + l * 4);
            ushort4 u3 = *(const ushort4*)(go_h + (size_t)g3 * 256 + l * 4);
            a0 += bf2f(u0.x) + bf2f(u1.x) + bf2f(u2.x) + bf2f(u3.x);
            a1 += bf2f(u0.y) + bf2f(u1.y) + bf2f(u2.y) + bf2f(u3.y);
            a2 += bf2f(u0.z) + bf2f(u1.z) + bf2f(u2.z) + bf2f(u3.z);
            a3 += bf2f(u0.w) + bf2f(u1.w) + bf2f(u2.w) + bf2f(u3.w);
        }
        for (; i < d; ++i) {
            int g = srt[o0 + i];
            ushort4 u = *(const ushort4*)(go_h + (size_t)g * 256 + l * 4);
            a0 += bf2f(u.x); a1 += bf2f(u.y); a2 += bf2f(u.z); a3 += bf2f(u.w);
        }
        // overflow residue (only if bucket > CAP; never for this data)
        int dtot = d;
        for (int j = e0 + ecs; j < e1; ++j) {
            unsigned int pr = pairs[j];
            if ((int)(pr >> 16) == r) {
                ushort4 u = *(const ushort4*)(go_h + (size_t)(pr & 0xffffu) * 256 + l * 4);
                a0 += bf2f(u.x); a1 += bf2f(u.y); a2 += bf2f(u.z); a3 += bf2f(u.w);
                dtot++;
            }
        }
        float inv = 1.f / (float)max(dtot, 1);
        float4 pf = ((const float4*)(prot + (size_t)p * 256))[l];
        unsigned int* hp = (unsigned int*)(hcat + (size_t)p * 512);
        hp[2 * l]     = pack2(pf.x, pf.y);
        hp[2 * l + 1] = pack2(pf.z, pf.w);
        unsigned int* hq = hp + 128 + 2 * l;
        hq[0] = pack2(a0 * inv, a1 * inv);
        hq[1] = pack2(a2 * inv, a3 * inv);
        if (l == 0) counts[p] = dtot;
    }
}

// ---------------- LayerNorm over y[N][256] f32 -> out ----------------
__global__ __launch_bounds__(256) void ln_kernel(
        const float* __restrict__ y, const float* __restrict__ gamma,
        const float* __restrict__ beta, float* __restrict__ out, int N) {
    int lane = threadIdx.x & 63;
    int row = blockIdx.x * 4 + (threadIdx.x >> 6);
    if (row >= N) return;
    float4 v = ((const float4*)(y + (size_t)row * 256))[lane];
    float s = v.x + v.y + v.z + v.w;
#pragma unroll
    for (int o = 32; o >= 1; o >>= 1) s += __shfl_xor(s, o);
    float mu = s * (1.f / 256.f);
    float4 d; d.x = v.x - mu; d.y = v.y - mu; d.z = v.z - mu; d.w = v.w - mu;
    float q = d.x * d.x + d.y * d.y + d.z * d.z + d.w * d.w;
#pragma unroll
    for (int o = 32; o >= 1; o >>= 1) q += __shfl_xor(q, o);
    float rstd = rsqrtf(q * (1.f / 256.f) + LN_EPS);
    float4 g = ((const float4*)gamma)[lane];
    float4 b = ((const float4*)beta)[lane];
    float4 o4;
    o4.x = d.x * rstd * g.x + b.x; o4.y = d.y * rstd * g.y + b.y;
    o4.z = d.z * rstd * g.z + b.z; o4.w = d.w * rstd * g.w + b.w;
    ((float4*)(out + (size_t)row * 256))[lane] = o4;
}

extern "C" void kernel_launch(void* const* d_in, const int* in_sizes, int n_in,
                              void* d_out, int out_size, void* d_ws, size_t ws_size,
                              hipStream_t stream) {
    const float* prot  = (const float*)d_in[0];
    const float* go_x  = (const float*)d_in[1];
    const int*   edges = (const int*)d_in[2];
    const float* Wg    = (const float*)d_in[4];
    const float* bg    = (const float*)d_in[5];
    const float* W1    = (const float*)d_in[6];
    const float* b1    = (const float*)d_in[7];
    const float* W2    = (const float*)d_in[8];
    const float* b2    = (const float*)d_in[9];
    const float* gamma = (const float*)d_in[10];
    const float* beta  = (const float*)d_in[11];

    int N = in_sizes[0] / HID;
    int G = in_sizes[1] / GOD;
    int E = in_sizes[2] / 2;
    const int* dst = edges;
    const int* src = edges + E;
    int NB = (N + PB - 1) / PB;          // 782 for N=50000 (<= MAXNB)
    int chunk = (E + NBLK - 1) / NBLK;   // 12500

    uint8_t* w = (uint8_t*)d_ws;
    size_t off = 0;
    auto alloc = [&](size_t bytes) -> void* {
        void* p = w + off;
        off = (off + bytes + 255) & ~(size_t)255;
        return p;
    };
    unsigned short* go_h = (unsigned short*)alloc((size_t)G * HID * 2);
    unsigned short* hcat = (unsigned short*)alloc((size_t)N * 512 * 2);
    unsigned short* tmp  = (unsigned short*)alloc((size_t)N * HID * 2);
    int* counts  = (int*)alloc((size_t)N * 4);
    int* blk_cnt = (int*)alloc((size_t)NB * NBLK * 4);
    int* blk_off = (int*)alloc((size_t)NB * NBLK * 4);
    int* btot    = (int*)alloc((size_t)NB * 4);
    int* bbase   = (int*)alloc((size_t)(NB + 1) * 4);
    short* Wgt = (short*)alloc((size_t)256 * 256 * 2);
    short* W1t = (short*)alloc((size_t)256 * 512 * 2);
    short* W2t = (short*)alloc((size_t)256 * 256 * 2);
    unsigned int* pairs = (unsigned int*)tmp;  // alias: tmp unused until mlp1 (pairs dead by then)
    float* y = (float*)hcat;                   // alias: hcat dead after mlp1

    transpose_all_kernel<<<dim3(256), dim3(256), 0, stream>>>(Wg, W1, W2, Wgt, W1t, W2t);

    int rb = (N + 127) / 128;
    int rbg = (G + 127) / 128;

    // go_h = relu(go_x @ Wg + bg)   [A f32, K padded 200->256]
    gemm_mfma<256, GOD, GOD, true, 0><<<dim3(rbg, 2), dim3(256), 0, stream>>>(
        go_x, Wgt, bg, go_h, nullptr, nullptr, G);

    // deterministic counting-sort partition of edges into buckets
    blk_hist_kernel<<<dim3(NBLK), dim3(256), 0, stream>>>(dst, blk_cnt, E, NB, chunk);
    blk_scan_kernel<<<dim3(NB), dim3(64), 0, stream>>>(blk_cnt, blk_off, btot);
    bucket_scan_kernel<<<dim3(1), dim3(1024), 0, stream>>>(btot, bbase, NB, E);
    part_kernel<<<dim3(NBLK), dim3(256), 0, stream>>>(dst, src, bbase, blk_off, pairs, E, NB, chunk);

    // per-bucket local sort + wave-per-protein register aggregation (+ prot cast)
    agg_kernel<<<dim3(NB), dim3(256), 0, stream>>>(go_h, pairs, bbase, prot, hcat, counts, N);

    // tmp = relu(hcat @ W1 + b1)
    gemm_mfma<512, 512, 512, false, 0><<<dim3(rb, 2), dim3(256), 0, stream>>>(
        hcat, W1t, b1, tmp, nullptr, nullptr, N);

    // y = prot + present * (tmp @ W2 + b2)
    gemm_mfma<256, 256, 256, false, 1><<<dim3(rb, 2), dim3(256), 0, stream>>>(
        tmp, W2t, b2, y, prot, counts, N);

    ln_kernel<<<dim3((N + 3) / 4), dim3(256), 0, stream>>>(y, gamma, beta, (float*)d_out, N);
}

// Round 14
// 463.729 us; speedup vs baseline: 2.2143x; 1.0224x over previous
//
#include <hip/hip_runtime.h>
#include <hip/hip_bf16.h>
#include <stdint.h>

#define HID 256
#define GOD 200
#define LN_EPS 1e-5f
#define PB 32             // proteins per bucket
#define PBSH 5
#define NBLK 128          // partition blocks
#define MAXNB 1600        // LDS array bound (NB = ceil(N/32) = 1563)
#define CAP 4096          // staged edges per bucket (mean ~1024 for this data)

typedef __attribute__((ext_vector_type(8))) short short8;
typedef __attribute__((ext_vector_type(4))) float f32x4;

__device__ __forceinline__ float bf2f(unsigned short u) {
    union { unsigned int i; float f; } c; c.i = ((unsigned int)u) << 16; return c.f;
}
__device__ __forceinline__ unsigned short f2bf(float f) {
    union { float f; unsigned int i; } c; c.f = f;
    unsigned int x = c.i;
    return (unsigned short)((x + 0x7fffu + ((x >> 16) & 1u)) >> 16);
}
__device__ __forceinline__ unsigned int pack2(float a, float b) {
    return (unsigned int)f2bf(a) | ((unsigned int)f2bf(b) << 16);
}
__device__ __forceinline__ short8 pack8(float4 a, float4 b) {
    short8 r;
    r[0] = (short)f2bf(a.x); r[1] = (short)f2bf(a.y);
    r[2] = (short)f2bf(a.z); r[3] = (short)f2bf(a.w);
    r[4] = (short)f2bf(b.x); r[5] = (short)f2bf(b.y);
    r[6] = (short)f2bf(b.z); r[7] = (short)f2bf(b.w);
    return r;
}

// ---------------- fused weight transpose + bf16 cast ----------------
__global__ void transpose_all_kernel(const float* __restrict__ Wg, const float* __restrict__ W1,
                                     const float* __restrict__ W2, short* __restrict__ Wgt,
                                     short* __restrict__ W1t, short* __restrict__ W2t) {
    const int TOT = 65536 + 131072 + 65536;
    for (int idx = blockIdx.x * 256 + threadIdx.x; idx < TOT; idx += gridDim.x * 256) {
        if (idx < 65536) {
            int c = idx >> 8, k = idx & 255;
            Wgt[idx] = (short)f2bf(k < GOD ? Wg[(size_t)k * 256 + c] : 0.f);
        } else if (idx < 65536 + 131072) {
            int j = idx - 65536;
            int c = j >> 9, k = j & 511;
            W1t[j] = (short)f2bf(W1[(size_t)k * 256 + c]);
        } else {
            int j = idx - (65536 + 131072);
            int c = j >> 8, k = j & 255;
            W2t[j] = (short)f2bf(W2[(size_t)k * 256 + c]);
        }
    }
}

// ---------------- MFMA GEMM (verified r4) — EPI 0: relu -> bf16 ----------------
template<int K, int ASTRIDE, int AK, bool AF32>
__global__ __launch_bounds__(256) void gemm_mfma(
        const void* __restrict__ Ap, const short* __restrict__ Bt,
        const float* __restrict__ bias, void* __restrict__ outp, int M) {
    __shared__ short As[128][88];
    __shared__ short Bs[128][88];

    const int t = threadIdx.x;
    const int row0 = blockIdx.x * 128;
    const int col0 = blockIdx.y * 128;
    const int lane = t & 63, w = t >> 6, wr = w >> 1, wc = w & 1;

    f32x4 acc[4][4] = {};

    for (int kt = 0; kt < K / 64; ++kt) {
        const int k0 = kt * 64;
        short8 ar[4], br[4];
#pragma unroll
        for (int i = 0; i < 4; ++i) {
            int seg = t + i * 256;
            int r = seg >> 3, co = (seg & 7) * 8;
            if (AF32) {
                short8 v = {};
                if (row0 + r < M && k0 + co + 8 <= AK) {
                    const float* ap = (const float*)Ap + (size_t)(row0 + r) * ASTRIDE + k0 + co;
                    float4 f0 = *(const float4*)ap;
                    float4 f1 = *(const float4*)(ap + 4);
                    v = pack8(f0, f1);
                }
                ar[i] = v;
            } else {
                short8 v = {};
                if (row0 + r < M)
                    v = *(const short8*)((const short*)Ap + (size_t)(row0 + r) * ASTRIDE + k0 + co);
                ar[i] = v;
            }
            br[i] = *(const short8*)(Bt + (size_t)(col0 + r) * K + k0 + co);
        }
        __syncthreads();
#pragma unroll
        for (int i = 0; i < 4; ++i) {
            int seg = t + i * 256;
            int r = seg >> 3, co = (seg & 7) * 8;
            *(short8*)&As[r][co] = ar[i];
            *(short8*)&Bs[r][co] = br[i];
        }
        __syncthreads();
#pragma unroll
        for (int ks = 0; ks < 2; ++ks) {
            short8 af[4], bf[4];
#pragma unroll
            for (int mt = 0; mt < 4; ++mt)
                af[mt] = *(const short8*)&As[wr * 64 + mt * 16 + (lane & 15)][ks * 32 + (lane >> 4) * 8];
#pragma unroll
            for (int nt = 0; nt < 4; ++nt)
                bf[nt] = *(const short8*)&Bs[wc * 64 + nt * 16 + (lane & 15)][ks * 32 + (lane >> 4) * 8];
#pragma unroll
            for (int mt = 0; mt < 4; ++mt)
#pragma unroll
                for (int nt = 0; nt < 4; ++nt)
                    acc[mt][nt] = __builtin_amdgcn_mfma_f32_16x16x32_bf16(af[mt], bf[nt], acc[mt][nt], 0, 0, 0);
        }
    }

#pragma unroll
    for (int nt = 0; nt < 4; ++nt) {
        int cg = col0 + wc * 64 + nt * 16 + (lane & 15);
        float bb = bias[cg];
#pragma unroll
        for (int mt = 0; mt < 4; ++mt) {
            int rbase = row0 + wr * 64 + mt * 16 + ((lane >> 4) * 4);
#pragma unroll
            for (int j = 0; j < 4; ++j) {
                int rg = rbase + j;
                if (rg < M) {
                    float v = acc[mt][nt][j] + bb;
                    ((unsigned short*)outp)[(size_t)rg * 256 + cg] = f2bf(fmaxf(v, 0.f));
                }
            }
        }
    }
}

// ---------------- mlp2 + residual + LayerNorm, full-width 128x256 tile ----------------
// 512 threads = 8 waves (2 row-groups x 4 col-groups), K=256 in 4 tiles.
__global__ __launch_bounds__(512) void mlp2_ln_kernel(
        const unsigned short* __restrict__ tmp, const short* __restrict__ W2t,
        const float* __restrict__ b2, const float* __restrict__ prot,
        const int* __restrict__ counts, const float* __restrict__ gamma,
        const float* __restrict__ beta, float* __restrict__ out, int M) {
    __shared__ short As[128][88];
    __shared__ short Bs[256][88];
    __shared__ float psum[128][4];
    __shared__ float psq[128][4];

    const int t = threadIdx.x;
    const int row0 = blockIdx.x * 128;
    const int lane = t & 63, w = t >> 6, wr = w >> 2, wc = w & 3;

    f32x4 acc[4][4] = {};

    for (int kt = 0; kt < 4; ++kt) {
        const int k0 = kt * 64;
        short8 ar[2], br[4];
#pragma unroll
        for (int i = 0; i < 2; ++i) {
            int seg = t + i * 512;
            int r = seg >> 3, co = (seg & 7) * 8;
            short8 v = {};
            if (row0 + r < M)
                v = *(const short8*)(tmp + (size_t)(row0 + r) * 256 + k0 + co);
            ar[i] = v;
        }
#pragma unroll
        for (int i = 0; i < 4; ++i) {
            int seg = t + i * 512;
            int r = seg >> 3, co = (seg & 7) * 8;
            br[i] = *(const short8*)(W2t + (size_t)r * 256 + k0 + co);
        }
        __syncthreads();
#pragma unroll
        for (int i = 0; i < 2; ++i) {
            int seg = t + i * 512;
            int r = seg >> 3, co = (seg & 7) * 8;
            *(short8*)&As[r][co] = ar[i];
        }
#pragma unroll
        for (int i = 0; i < 4; ++i) {
            int seg = t + i * 512;
            int r = seg >> 3, co = (seg & 7) * 8;
            *(short8*)&Bs[r][co] = br[i];
        }
        __syncthreads();
#pragma unroll
        for (int ks = 0; ks < 2; ++ks) {
            short8 af[4], bf[4];
#pragma unroll
            for (int mt = 0; mt < 4; ++mt)
                af[mt] = *(const short8*)&As[wr * 64 + mt * 16 + (lane & 15)][ks * 32 + (lane >> 4) * 8];
#pragma unroll
            for (int nt = 0; nt < 4; ++nt)
                bf[nt] = *(const short8*)&Bs[wc * 64 + nt * 16 + (lane & 15)][ks * 32 + (lane >> 4) * 8];
#pragma unroll
            for (int mt = 0; mt < 4; ++mt)
#pragma unroll
                for (int nt = 0; nt < 4; ++nt)
                    acc[mt][nt] = __builtin_amdgcn_mfma_f32_16x16x32_bf16(af[mt], bf[nt], acc[mt][nt], 0, 0, 0);
        }
    }

    // ---- epilogue: y = prot + pres*(acc + b2); per-row partial sums; LN ----
    float bb[4];
#pragma unroll
    for (int nt = 0; nt < 4; ++nt) bb[nt] = b2[wc * 64 + nt * 16 + (lane & 15)];

#pragma unroll
    for (int mt = 0; mt < 4; ++mt) {
#pragma unroll
        for (int j = 0; j < 4; ++j) {
            int rloc = wr * 64 + mt * 16 + ((lane >> 4) * 4) + j;
            int rg = row0 + rloc;
            float pres = 0.f;
            if (rg < M) pres = (counts[rg] > 0) ? 1.f : 0.f;
            float s = 0.f, q = 0.f;
#pragma unroll
            for (int nt = 0; nt < 4; ++nt) {
                int cg = wc * 64 + nt * 16 + (lane & 15);
                float pv = (rg < M) ? prot[(size_t)rg * 256 + cg] : 0.f;
                float yv = pv + pres * (acc[mt][nt][j] + bb[nt]);
                acc[mt][nt][j] = yv;
                s += yv;
                q += yv * yv;
            }
#pragma unroll
            for (int o = 1; o < 16; o <<= 1) {
                s += __shfl_xor(s, o);
                q += __shfl_xor(q, o);
            }
            if ((lane & 15) == 0) {
                psum[rloc][wc] = s;
                psq[rloc][wc] = q;
            }
        }
    }
    __syncthreads();

#pragma unroll
    for (int mt = 0; mt < 4; ++mt) {
#pragma unroll
        for (int j = 0; j < 4; ++j) {
            int rloc = wr * 64 + mt * 16 + ((lane >> 4) * 4) + j;
            int rg = row0 + rloc;
            if (rg >= M) continue;
            float s = psum[rloc][0] + psum[rloc][1] + psum[rloc][2] + psum[rloc][3];
            float q = psq[rloc][0] + psq[rloc][1] + psq[rloc][2] + psq[rloc][3];
            float mu = s * (1.f / 256.f);
            float var = q * (1.f / 256.f) - mu * mu;
            float rstd = rsqrtf(var + LN_EPS);
#pragma unroll
            for (int nt = 0; nt < 4; ++nt) {
                int cg = wc * 64 + nt * 16 + (lane & 15);
                float o4 = (acc[mt][nt][j] - mu) * rstd * gamma[cg] + beta[cg];
                out[(size_t)rg * 256 + cg] = o4;
            }
        }
    }
}

// ---------------- counting-sort partition ----------------
__global__ __launch_bounds__(256) void blk_hist_kernel(
        const int* __restrict__ dst, int* __restrict__ blk_cnt, int E, int NB, int chunk) {
    __shared__ int h[MAXNB];
    int k = blockIdx.x, tid = threadIdx.x;
    for (int i = tid; i < NB; i += 256) h[i] = 0;
    __syncthreads();
    int s0 = k * chunk, s1 = min(E, s0 + chunk);
    for (int e = s0 + tid; e < s1; e += 256) atomicAdd(&h[dst[e] >> PBSH], 1);
    __syncthreads();
    for (int i = tid; i < NB; i += 256) blk_cnt[(size_t)i * NBLK + k] = h[i];
}

__global__ __launch_bounds__(64) void blk_scan_kernel(
        const int* __restrict__ blk_cnt, int* __restrict__ blk_off, int* __restrict__ btot) {
    int b = blockIdx.x, l = threadIdx.x;
    int v0 = blk_cnt[(size_t)b * NBLK + 2 * l];
    int v1 = blk_cnt[(size_t)b * NBLK + 2 * l + 1];
    int s = v0 + v1;
#pragma unroll
    for (int o = 1; o < 64; o <<= 1) { int y = __shfl_up(s, o); if (l >= o) s += y; }
    int excl = s - (v0 + v1);
    blk_off[(size_t)b * NBLK + 2 * l]     = excl;
    blk_off[(size_t)b * NBLK + 2 * l + 1] = excl + v0;
    if (l == 63) btot[b] = s;
}

// looped scan with carry (NB may exceed 1024)
__global__ __launch_bounds__(1024) void bucket_scan_kernel(
        const int* __restrict__ btot, int* __restrict__ bbase, int NB, int E) {
    __shared__ int sc[1024];
    __shared__ int carry;
    int tid = threadIdx.x;
    if (tid == 0) carry = 0;
    __syncthreads();
    for (int base = 0; base < NB; base += 1024) {
        int i = base + tid;
        int v = (i < NB) ? btot[i] : 0;
        sc[tid] = v;
        __syncthreads();
        for (int o = 1; o < 1024; o <<= 1) {
            int add = (tid >= o) ? sc[tid - o] : 0;
            __syncthreads();
            sc[tid] += add;
            __syncthreads();
        }
        if (i < NB) bbase[i] = carry + sc[tid] - v;
        __syncthreads();
        if (tid == 0) carry += sc[1023];
        __syncthreads();
    }
    if (tid == 0) bbase[NB] = E;
}

__global__ __launch_bounds__(256) void part_kernel(
        const int* __restrict__ dst, const int* __restrict__ src,
        const int* __restrict__ bbase, const int* __restrict__ blk_off,
        unsigned int* __restrict__ pairs, int E, int NB, int chunk) {
    __shared__ int cur[MAXNB];
    int k = blockIdx.x, tid = threadIdx.x;
    for (int i = tid; i < NB; i += 256)
        cur[i] = bbase[i] + blk_off[(size_t)i * NBLK + k];
    __syncthreads();
    int s0 = k * chunk, s1 = min(E, s0 + chunk);
    for (int e = s0 + tid; e < s1; e += 256) {
        int d = dst[e];
        unsigned int pr = ((unsigned int)(d & (PB - 1)) << 16) | (unsigned int)src[e];
        int slot = atomicAdd(&cur[d >> PBSH], 1);
        pairs[slot] = pr;
    }
}

// ---------------- aggregation: per-bucket local sort + wave-per-protein reg accum ----------------
__global__ __launch_bounds__(256) void agg_kernel(
        const unsigned short* __restrict__ go_h, const unsigned int* __restrict__ pairs,
        const int* __restrict__ bbase, const float* __restrict__ prot,
        unsigned short* __restrict__ hcat, int* __restrict__ counts, int N) {
    __shared__ unsigned short srt[CAP];
    __shared__ int cnt[PB], off[PB], cur[PB];
    int b = blockIdx.x, tid = threadIdx.x, w = tid >> 6, l = tid & 63;
    int e0 = bbase[b], e1 = bbase[b + 1];
    int ec = e1 - e0;
    int ecs = min(ec, CAP);   // staged (sorted) portion; overflow handled at the end

    if (tid < PB) cnt[tid] = 0;
    __syncthreads();
    for (int i = tid; i < ecs; i += 256)
        atomicAdd(&cnt[pairs[e0 + i] >> 16], 1);
    __syncthreads();
    if (w == 0) {
        int v = (l < PB) ? cnt[l] : 0;
        int s = v;
#pragma unroll
        for (int o = 1; o < PB; o <<= 1) { int y = __shfl_up(s, o); if (l >= o) s += y; }
        if (l < PB) { off[l] = s - v; cur[l] = s - v; }
    }
    __syncthreads();
    for (int i = tid; i < ecs; i += 256) {
        unsigned int pr = pairs[e0 + i];
        int slot = atomicAdd(&cur[pr >> 16], 1);
        srt[slot] = (unsigned short)(pr & 0xffffu);
    }
    __syncthreads();

    int p0g = b << PBSH;
    for (int r = w; r < PB; r += 4) {
        int p = p0g + r;
        if (p >= N) break;
        int o0 = off[r], d = cnt[r];
        float a0 = 0.f, a1 = 0.f, a2 = 0.f, a3 = 0.f;
        int i = 0;
        for (; i + 4 <= d; i += 4) {
            int g0 = srt[o0 + i], g1 = srt[o0 + i + 1];
            int g2 = srt[o0 + i + 2], g3 = srt[o0 + i + 3];
            ushort4 u0 = *(const ushort4*)(go_h + (size_t)g0 * 256 + l * 4);
            ushort4 u1 = *(const ushort4*)(go_h + (size_t)g1 * 256 + l * 4);
            ushort4 u2 = *(const ushort4*)(go_h + (size_t)g2 * 256 + l * 4);
            ushort4 u3 = *(const ushort4*)(go_h + (size_t)g3 * 256 + l * 4);
            a0 += bf2f(u0.x) + bf2f(u1.x) + bf2f(u2.x) + bf2f(u3.x);
            a1 += bf2f(u0.y) + bf2f(u1.y) + bf2f(u2.y) + bf2f(u3.y);
            a2 += bf2f(u0.z) + bf2f(u1.z) + bf2f(u2.z) + bf2f(u3.z);
            a3 += bf2f(u0.w) + bf2f(u1.w) + bf2f(u2.w) + bf2f(u3.w);
        }
        for (; i < d; ++i) {
            int g = srt[o0 + i];
            ushort4 u = *(const ushort4*)(go_h + (size_t)g * 256 + l * 4);
            a0 += bf2f(u.x); a1 += bf2f(u.y); a2 += bf2f(u.z); a3 += bf2f(u.w);
        }
        int dtot = d;
        for (int j = e0 + ecs; j < e1; ++j) {
            unsigned int pr = pairs[j];
            if ((int)(pr >> 16) == r) {
                ushort4 u = *(const ushort4*)(go_h + (size_t)(pr & 0xffffu) * 256 + l * 4);
                a0 += bf2f(u.x); a1 += bf2f(u.y); a2 += bf2f(u.z); a3 += bf2f(u.w);
                dtot++;
            }
        }
        float inv = 1.f / (float)max(dtot, 1);
        float4 pf = ((const float4*)(prot + (size_t)p * 256))[l];
        unsigned int* hp = (unsigned int*)(hcat + (size_t)p * 512);
        hp[2 * l]     = pack2(pf.x, pf.y);
        hp[2 * l + 1] = pack2(pf.z, pf.w);
        unsigned int* hq = hp + 128 + 2 * l;
        hq[0] = pack2(a0 * inv, a1 * inv);
        hq[1] = pack2(a2 * inv, a3 * inv);
        if (l == 0) counts[p] = dtot;
    }
}

extern "C" void kernel_launch(void* const* d_in, const int* in_sizes, int n_in,
                              void* d_out, int out_size, void* d_ws, size_t ws_size,
                              hipStream_t stream) {
    const float* prot  = (const float*)d_in[0];
    const float* go_x  = (const float*)d_in[1];
    const int*   edges = (const int*)d_in[2];
    const float* Wg    = (const float*)d_in[4];
    const float* bg    = (const float*)d_in[5];
    const float* W1    = (const float*)d_in[6];
    const float* b1    = (const float*)d_in[7];
    const float* W2    = (const float*)d_in[8];
    const float* b2    = (const float*)d_in[9];
    const float* gamma = (const float*)d_in[10];
    const float* beta  = (const float*)d_in[11];

    int N = in_sizes[0] / HID;
    int G = in_sizes[1] / GOD;
    int E = in_sizes[2] / 2;
    const int* dst = edges;
    const int* src = edges + E;
    int NB = (N + PB - 1) / PB;          // 1563 for N=50000 (<= MAXNB)
    int chunk = (E + NBLK - 1) / NBLK;   // 12500

    uint8_t* w = (uint8_t*)d_ws;
    size_t off = 0;
    auto alloc = [&](size_t bytes) -> void* {
        void* p = w + off;
        off = (off + bytes + 255) & ~(size_t)255;
        return p;
    };
    unsigned short* go_h = (unsigned short*)alloc((size_t)G * HID * 2);
    unsigned short* hcat = (unsigned short*)alloc((size_t)N * 512 * 2);
    unsigned short* tmp  = (unsigned short*)alloc((size_t)N * HID * 2);
    int* counts  = (int*)alloc((size_t)N * 4);
    int* blk_cnt = (int*)alloc((size_t)NB * NBLK * 4);
    int* blk_off = (int*)alloc((size_t)NB * NBLK * 4);
    int* btot    = (int*)alloc((size_t)NB * 4);
    int* bbase   = (int*)alloc((size_t)(NB + 1) * 4);
    short* Wgt = (short*)alloc((size_t)256 * 256 * 2);
    short* W1t = (short*)alloc((size_t)256 * 512 * 2);
    short* W2t = (short*)alloc((size_t)256 * 256 * 2);
    unsigned int* pairs = (unsigned int*)tmp;  // alias: tmp unused until mlp1 (pairs dead by then)

    transpose_all_kernel<<<dim3(256), dim3(256), 0, stream>>>(Wg, W1, W2, Wgt, W1t, W2t);

    int rb = (N + 127) / 128;
    int rbg = (G + 127) / 128;

    // go_h = relu(go_x @ Wg + bg)   [A f32, K padded 200->256]
    gemm_mfma<256, GOD, GOD, true><<<dim3(rbg, 2), dim3(256), 0, stream>>>(
        go_x, Wgt, bg, go_h, G);

    // deterministic counting-sort partition of edges into buckets
    blk_hist_kernel<<<dim3(NBLK), dim3(256), 0, stream>>>(dst, blk_cnt, E, NB, chunk);
    blk_scan_kernel<<<dim3(NB), dim3(64), 0, stream>>>(blk_cnt, blk_off, btot);
    bucket_scan_kernel<<<dim3(1), dim3(1024), 0, stream>>>(btot, bbase, NB, E);
    part_kernel<<<dim3(NBLK), dim3(256), 0, stream>>>(dst, src, bbase, blk_off, pairs, E, NB, chunk);

    // per-bucket local sort + wave-per-protein register aggregation (+ prot cast)
    agg_kernel<<<dim3(NB), dim3(256), 0, stream>>>(go_h, pairs, bbase, prot, hcat, counts, N);

    // tmp = relu(hcat @ W1 + b1)
    gemm_mfma<512, 512, 512, false><<<dim3(rb, 2), dim3(256), 0, stream>>>(
        hcat, W1t, b1, tmp, N);

    // out = LayerNorm(prot + present * (tmp @ W2 + b2))
    mlp2_ln_kernel<<<dim3(rb), dim3(512), 0, stream>>>(
        tmp, W2t, b2, prot, counts, gamma, beta, (float*)d_out, N);
}